// Round 2
// baseline (502.545 us; speedup 1.0000x reference)
//
#include <hip/hip_runtime.h>
#include <hip/hip_bf16.h>

#define NN 10000
#define NE 250000
#define FEAT 16
#define EMB 32
#define HID 32
#define NV 12
#define EAD 9
#define NG 64

// ---------------------------------------------------------------------------
// degree count: cnt[dst] += 1 per edge
// ---------------------------------------------------------------------------
__global__ void count_deg_kernel(const int* __restrict__ dst, float* __restrict__ cnt) {
    int e = blockIdx.x * blockDim.x + threadIdx.x;
    if (e < NE) atomicAdd(&cnt[dst[e]], 1.0f);
}

// ---------------------------------------------------------------------------
// Q[n,k,o] = sum_i h[n,i] * w2[k, i*32+o]   (k<32)
// Q[n,32,o] = sum_i h[n,i] * b2[i*32+o]     (bias row)
// Layout: Q[(n*33 + k)*32 + o], total N*33*32 elements.
// ---------------------------------------------------------------------------
template <int DIN>
__global__ void computeQ_kernel(const float* __restrict__ h,   // [N, DIN]
                                const float* __restrict__ w2,  // [32, DIN*32]
                                const float* __restrict__ b2,  // [DIN*32]
                                float* __restrict__ Q)         // [N, 33, 32]
{
    int idx = blockIdx.x * blockDim.x + threadIdx.x;
    if (idx >= NN * 33 * 32) return;
    int o = idx & 31;
    int k = (idx >> 5) % 33;
    int n = idx / (33 * 32);
    const float* hn = h + n * DIN;
    float s = 0.f;
    if (k < 32) {
        const float* w = w2 + k * (DIN * 32);
#pragma unroll
        for (int i = 0; i < DIN; ++i) s += hn[i] * w[i * 32 + o];
    } else {
#pragma unroll
        for (int i = 0; i < DIN; ++i) s += hn[i] * b2[i * 32 + o];
    }
    Q[idx] = s;
}

// ---------------------------------------------------------------------------
// Per-edge: hidden = relu(ea @ w1 + b1) [32]; msg[o] = Q[src,32,o] +
// sum_k hidden[k]*Q[src,k,o]; atomicAdd into agg[dst,o].
// 256 threads = 8 edges x 32 outputs. NE % 8 == 0 so no bounds check.
// ---------------------------------------------------------------------------
__global__ __launch_bounds__(256) void conv_edges_kernel(
    const float* __restrict__ ea,   // [E, 9]
    const int* __restrict__ src,
    const int* __restrict__ dst,
    const float* __restrict__ w1,   // [9, 32]
    const float* __restrict__ b1,   // [32]
    const float* __restrict__ Q,    // [N, 33, 32]
    float* __restrict__ agg)        // [N, 32]
{
    __shared__ float s_w1[EAD * 32];
    __shared__ float s_b1[32];
    __shared__ float s_hidden[8][32];

    int t = threadIdx.x;
    if (t < EAD * 32) s_w1[t] = w1[t];
    if (t < 32) s_b1[t] = b1[t];
    __syncthreads();

    int le = t >> 5;       // 0..7 edge slot within block
    int o  = t & 31;       // output index
    int e  = blockIdx.x * 8 + le;

    // edge MLP hidden unit o for edge e
    const float* eav = ea + e * EAD;
    float hsum = s_b1[o];
#pragma unroll
    for (int j = 0; j < EAD; ++j) hsum += eav[j] * s_w1[j * 32 + o];
    s_hidden[le][o] = fmaxf(hsum, 0.f);
    __syncthreads();

    const float* q = Q + (size_t)src[e] * (33 * 32);
    float m = q[32 * 32 + o];  // bias row
#pragma unroll
    for (int k = 0; k < 32; ++k) m += s_hidden[le][k] * q[k * 32 + o];

    atomicAdd(&agg[dst[e] * 32 + o], m);
}

// ---------------------------------------------------------------------------
// hout[n,o] = relu(agg[n,o]/max(cnt,1) + sum_i hin[n,i]*root[i,o] + bias[o])
// Optionally fuse graph pooling atomics (pass pooled != nullptr).
// ---------------------------------------------------------------------------
template <int DIN>
__global__ void node_update_kernel(const float* __restrict__ agg,
                                   const float* __restrict__ cnt,
                                   const float* __restrict__ hin,   // [N, DIN]
                                   const float* __restrict__ root,  // [DIN, 32]
                                   const float* __restrict__ bias,  // [32]
                                   float* __restrict__ hout,        // [N, 32]
                                   float* __restrict__ pooled,      // [G,32] or null
                                   const int* __restrict__ batch,
                                   float* __restrict__ gcnt)        // [G] or null
{
    int idx = blockIdx.x * blockDim.x + threadIdx.x;
    if (idx >= NN * 32) return;
    int o = idx & 31;
    int n = idx >> 5;
    float s = bias[o] + agg[idx] / fmaxf(cnt[n], 1.0f);
    const float* h = hin + n * DIN;
    const float* r = root;
#pragma unroll
    for (int i = 0; i < DIN; ++i) s += h[i] * r[i * 32 + o];
    s = fmaxf(s, 0.f);
    hout[idx] = s;
    if (pooled) {
        int g = batch[n];
        atomicAdd(&pooled[g * 32 + o], s);
        if (o == 0) atomicAdd(&gcnt[g], 1.0f);
    }
}

// ---------------------------------------------------------------------------
// Final: pooled mean -> linear(32,12) -> log_softmax. One thread per graph.
// ---------------------------------------------------------------------------
__global__ void final_kernel(const float* __restrict__ pooled,
                             const float* __restrict__ gcnt,
                             const float* __restrict__ lin_w,  // [32, 12]
                             const float* __restrict__ lin_b,  // [12]
                             float* __restrict__ out)          // [64, 12]
{
    int g = threadIdx.x;
    if (g >= NG) return;
    float inv = 1.0f / fmaxf(gcnt[g], 1.0f);
    float p[HID];
#pragma unroll
    for (int h = 0; h < HID; ++h) p[h] = pooled[g * HID + h] * inv;
    float logits[NV];
    float mx = -1e30f;
#pragma unroll
    for (int v = 0; v < NV; ++v) {
        float s = lin_b[v];
#pragma unroll
        for (int h = 0; h < HID; ++h) s += p[h] * lin_w[h * NV + v];
        logits[v] = s;
        mx = fmaxf(mx, s);
    }
    float se = 0.f;
#pragma unroll
    for (int v = 0; v < NV; ++v) se += expf(logits[v] - mx);
    float lse = mx + logf(se);
#pragma unroll
    for (int v = 0; v < NV; ++v) out[g * NV + v] = logits[v] - lse;
}

// ---------------------------------------------------------------------------
extern "C" void kernel_launch(void* const* d_in, const int* in_sizes, int n_in,
                              void* d_out, int out_size, void* d_ws, size_t ws_size,
                              hipStream_t stream) {
    const float* x        = (const float*)d_in[0];   // [N,16]
    const float* ea       = (const float*)d_in[1];   // [E,9]
    const int*   eidx     = (const int*)d_in[2];     // [2,E]
    const int*   batch    = (const int*)d_in[3];     // [N]
    const float* nn1_w1   = (const float*)d_in[4];
    const float* nn1_b1   = (const float*)d_in[5];
    const float* nn1_w2   = (const float*)d_in[6];
    const float* nn1_b2   = (const float*)d_in[7];
    const float* root1    = (const float*)d_in[8];
    const float* bias1    = (const float*)d_in[9];
    const float* nn2_w1   = (const float*)d_in[10];
    const float* nn2_b1   = (const float*)d_in[11];
    const float* nn2_w2   = (const float*)d_in[12];
    const float* nn2_b2   = (const float*)d_in[13];
    const float* root2    = (const float*)d_in[14];
    const float* bias2    = (const float*)d_in[15];
    const float* lin_w    = (const float*)d_in[16];
    const float* lin_b    = (const float*)d_in[17];
    float* out = (float*)d_out;

    const int* src = eidx;
    const int* dst = eidx + NE;

    // workspace layout (floats)
    float* ws     = (float*)d_ws;
    float* Q      = ws;                       // N*33*32 = 10,560,000
    float* agg    = Q + (size_t)NN * 33 * 32; // 320,000
    float* cnt    = agg + NN * 32;            // 10,000
    float* h1     = cnt + NN;                 // 320,000
    float* h2     = h1 + NN * 32;             // 320,000
    float* pooled = h2 + NN * 32;             // 2048
    float* gcnt   = pooled + NG * HID;        // 64

    // zero accumulators (fresh every call; harness does not re-poison)
    hipMemsetAsync(cnt, 0, NN * sizeof(float), stream);
    hipMemsetAsync(agg, 0, NN * 32 * sizeof(float), stream);
    hipMemsetAsync(pooled, 0, NG * HID * sizeof(float), stream);
    hipMemsetAsync(gcnt, 0, NG * sizeof(float), stream);

    count_deg_kernel<<<(NE + 255) / 256, 256, 0, stream>>>(dst, cnt);

    // ---- conv1 ----
    computeQ_kernel<FEAT><<<(NN * 33 * 32) / 256, 256, 0, stream>>>(x, nn1_w2, nn1_b2, Q);
    conv_edges_kernel<<<NE / 8, 256, 0, stream>>>(ea, src, dst, nn1_w1, nn1_b1, Q, agg);
    node_update_kernel<FEAT><<<(NN * 32) / 256, 256, 0, stream>>>(
        agg, cnt, x, root1, bias1, h1, nullptr, nullptr, nullptr);

    // ---- conv2 ----
    hipMemsetAsync(agg, 0, NN * 32 * sizeof(float), stream);
    computeQ_kernel<EMB><<<(NN * 33 * 32) / 256, 256, 0, stream>>>(h1, nn2_w2, nn2_b2, Q);
    conv_edges_kernel<<<NE / 8, 256, 0, stream>>>(ea, src, dst, nn2_w1, nn2_b1, Q, agg);
    node_update_kernel<EMB><<<(NN * 32) / 256, 256, 0, stream>>>(
        agg, cnt, h1, root2, bias2, h2, pooled, batch, gcnt);

    // ---- head ----
    final_kernel<<<1, 64, 0, stream>>>(pooled, gcnt, lin_w, lin_b, out);
}

// Round 3
// 417.039 us; speedup vs baseline: 1.2050x; 1.2050x over previous
//
#include <hip/hip_runtime.h>
#include <hip/hip_bf16.h>

#define NN 10000
#define NE 250000
#define FEAT 16
#define EMB 32
#define HID 32
#define NV 12
#define EAD 9
#define NG 64

// ---------------------------------------------------------------------------
// One pass over edges: src out-degree histogram (int) + dst in-degree (float)
// ---------------------------------------------------------------------------
__global__ void edge_stats_kernel(const int* __restrict__ src,
                                  const int* __restrict__ dst,
                                  int* __restrict__ hist,
                                  float* __restrict__ cnt) {
    int e = blockIdx.x * blockDim.x + threadIdx.x;
    if (e >= NE) return;
    atomicAdd(&hist[src[e]], 1);
    atomicAdd(&cnt[dst[e]], 1.0f);
}

// ---------------------------------------------------------------------------
// Single-block exclusive scan of hist[NN] -> rowStart[NN+1], cursor[NN]
// 1024 threads x 10 bins each, Hillis-Steele over partials.
// ---------------------------------------------------------------------------
__global__ __launch_bounds__(1024) void scan_kernel(const int* __restrict__ hist,
                                                    int* __restrict__ rowStart,
                                                    int* __restrict__ cursor) {
    __shared__ int part[1024];
    int t = threadIdx.x;
    int base = t * 10;
    int local[10];
    int s = 0;
#pragma unroll
    for (int i = 0; i < 10; ++i) {
        int v = (base + i < NN) ? hist[base + i] : 0;
        local[i] = s;
        s += v;
    }
    part[t] = s;
    __syncthreads();
    for (int off = 1; off < 1024; off <<= 1) {
        int v = (t >= off) ? part[t - off] : 0;
        __syncthreads();
        part[t] += v;
        __syncthreads();
    }
    int pre = (t == 0) ? 0 : part[t - 1];
#pragma unroll
    for (int i = 0; i < 10; ++i) {
        if (base + i < NN) {
            int rs = pre + local[i];
            rowStart[base + i] = rs;
            cursor[base + i] = rs;
        }
    }
    if (t == 1023) rowStart[NN] = part[1023];
}

// ---------------------------------------------------------------------------
// Permute edges into src-sorted order.
// ---------------------------------------------------------------------------
__global__ void scatter_kernel(const float* __restrict__ ea,
                               const int* __restrict__ src,
                               const int* __restrict__ dst,
                               int* __restrict__ cursor,
                               float* __restrict__ ea_s,
                               int* __restrict__ src_s,
                               int* __restrict__ dst_s) {
    int e = blockIdx.x * blockDim.x + threadIdx.x;
    if (e >= NE) return;
    int sv = src[e];
    int pos = atomicAdd(&cursor[sv], 1);
    src_s[pos] = sv;
    dst_s[pos] = dst[e];
#pragma unroll
    for (int j = 0; j < EAD; ++j) ea_s[(size_t)pos * EAD + j] = ea[(size_t)e * EAD + j];
}

// ---------------------------------------------------------------------------
// Fused NNConv message pass: block = 8 consecutive source nodes.
//  1) compute Q rows [8][33*32] in LDS (Q[k,o]=sum_i h[i]*w2[k,i*32+o];
//     row 32 = bias term sum_i h[i]*b2[i*32+o])
//  2) walk the 8 nodes' contiguous sorted edge range, 8 edges x 32 lanes:
//     hidden = relu(ea@w1+b1); msg[o] = Qb[o] + sum_k hidden[k]*Q[k,o];
//     atomicAdd into agg[dst].
// ---------------------------------------------------------------------------
template <int DIN>
__global__ __launch_bounds__(256) void conv_node_kernel(
    const float* __restrict__ h,        // [N, DIN]
    const float* __restrict__ w1,       // [9,32]
    const float* __restrict__ b1,       // [32]
    const float* __restrict__ w2,       // [32, DIN*32]
    const float* __restrict__ b2,       // [DIN*32]
    const int* __restrict__ rowStart,   // [N+1]
    const float* __restrict__ ea_s,     // [E,9] src-sorted
    const int* __restrict__ src_s,      // [E]
    const int* __restrict__ dst_s,      // [E]
    float* __restrict__ agg)            // [N,32]
{
    __shared__ float s_Q[8][33 * 32];
    __shared__ float s_h[8][DIN];
    __shared__ float s_w1[EAD * 32];
    __shared__ float s_b1[32];
    __shared__ float s_hidden[8][32];

    int t = threadIdx.x;
    int n0 = blockIdx.x * 8;

    if (t < EAD * 32) s_w1[t] = w1[t];
    if (t < 32) s_b1[t] = b1[t];
    if (t < 8 * DIN) s_h[t / DIN][t % DIN] = h[(size_t)n0 * DIN + t];
    __syncthreads();

    // ---- Q rows for the 8 nodes; w2 element read ONCE per block ----
    for (int idx = t; idx < 33 * 32; idx += 256) {
        int o = idx & 31;
        int k = idx >> 5;
        const float* w = (k < 32) ? (w2 + (size_t)k * (DIN * 32) + o) : (b2 + o);
        float acc[8];
#pragma unroll
        for (int nn = 0; nn < 8; ++nn) acc[nn] = 0.f;
#pragma unroll
        for (int i = 0; i < DIN; ++i) {
            float wv = w[i * 32];
#pragma unroll
            for (int nn = 0; nn < 8; ++nn) acc[nn] += s_h[nn][i] * wv;
        }
#pragma unroll
        for (int nn = 0; nn < 8; ++nn) s_Q[nn][idx] = acc[nn];
    }
    __syncthreads();

    // ---- contiguous edge range for nodes [n0, n0+8) ----
    int beg = rowStart[n0];
    int end = rowStart[n0 + 8];
    int le = t >> 5;   // edge slot 0..7
    int o  = t & 31;   // output column

    for (int base = beg; base < end; base += 8) {
        int e = base + le;
        bool valid = e < end;
        int d = 0, sl = 0;
        if (valid) {
            float hs = s_b1[o];
#pragma unroll
            for (int j = 0; j < EAD; ++j) hs += ea_s[(size_t)e * EAD + j] * s_w1[j * 32 + o];
            s_hidden[le][o] = fmaxf(hs, 0.f);
            d = dst_s[e];
            sl = src_s[e] - n0;
        }
        __syncthreads();
        if (valid) {
            const float* q = s_Q[sl];
            float m = q[32 * 32 + o];
#pragma unroll
            for (int k = 0; k < 32; ++k) m += s_hidden[le][k] * q[k * 32 + o];
            atomicAdd(&agg[(size_t)d * 32 + o], m);
        }
        __syncthreads();
    }
}

// ---------------------------------------------------------------------------
// hout[n,o] = relu(agg[n,o]/max(cnt,1) + sum_i hin[n,i]*root[i,o] + bias[o])
// Optionally fuse graph pooling atomics.
// ---------------------------------------------------------------------------
template <int DIN>
__global__ void node_update_kernel(const float* __restrict__ agg,
                                   const float* __restrict__ cnt,
                                   const float* __restrict__ hin,
                                   const float* __restrict__ root,
                                   const float* __restrict__ bias,
                                   float* __restrict__ hout,
                                   float* __restrict__ pooled,
                                   const int* __restrict__ batch,
                                   float* __restrict__ gcnt)
{
    int idx = blockIdx.x * blockDim.x + threadIdx.x;
    if (idx >= NN * 32) return;
    int o = idx & 31;
    int n = idx >> 5;
    float s = bias[o] + agg[idx] / fmaxf(cnt[n], 1.0f);
    const float* h = hin + (size_t)n * DIN;
#pragma unroll
    for (int i = 0; i < DIN; ++i) s += h[i] * root[i * 32 + o];
    s = fmaxf(s, 0.f);
    hout[idx] = s;
    if (pooled) {
        int g = batch[n];
        atomicAdd(&pooled[g * 32 + o], s);
        if (o == 0) atomicAdd(&gcnt[g], 1.0f);
    }
}

// ---------------------------------------------------------------------------
// Final: pooled mean -> linear(32,12) -> log_softmax. One thread per graph.
// ---------------------------------------------------------------------------
__global__ void final_kernel(const float* __restrict__ pooled,
                             const float* __restrict__ gcnt,
                             const float* __restrict__ lin_w,
                             const float* __restrict__ lin_b,
                             float* __restrict__ out)
{
    int g = threadIdx.x;
    if (g >= NG) return;
    float inv = 1.0f / fmaxf(gcnt[g], 1.0f);
    float p[HID];
#pragma unroll
    for (int h = 0; h < HID; ++h) p[h] = pooled[g * HID + h] * inv;
    float logits[NV];
    float mx = -1e30f;
#pragma unroll
    for (int v = 0; v < NV; ++v) {
        float s = lin_b[v];
#pragma unroll
        for (int h = 0; h < HID; ++h) s += p[h] * lin_w[h * NV + v];
        logits[v] = s;
        mx = fmaxf(mx, s);
    }
    float se = 0.f;
#pragma unroll
    for (int v = 0; v < NV; ++v) se += expf(logits[v] - mx);
    float lse = mx + logf(se);
#pragma unroll
    for (int v = 0; v < NV; ++v) out[g * NV + v] = logits[v] - lse;
}

// ---------------------------------------------------------------------------
extern "C" void kernel_launch(void* const* d_in, const int* in_sizes, int n_in,
                              void* d_out, int out_size, void* d_ws, size_t ws_size,
                              hipStream_t stream) {
    const float* x        = (const float*)d_in[0];
    const float* ea       = (const float*)d_in[1];
    const int*   eidx     = (const int*)d_in[2];
    const int*   batch    = (const int*)d_in[3];
    const float* nn1_w1   = (const float*)d_in[4];
    const float* nn1_b1   = (const float*)d_in[5];
    const float* nn1_w2   = (const float*)d_in[6];
    const float* nn1_b2   = (const float*)d_in[7];
    const float* root1    = (const float*)d_in[8];
    const float* bias1    = (const float*)d_in[9];
    const float* nn2_w1   = (const float*)d_in[10];
    const float* nn2_b1   = (const float*)d_in[11];
    const float* nn2_w2   = (const float*)d_in[12];
    const float* nn2_b2   = (const float*)d_in[13];
    const float* root2    = (const float*)d_in[14];
    const float* bias2    = (const float*)d_in[15];
    const float* lin_w    = (const float*)d_in[16];
    const float* lin_b    = (const float*)d_in[17];
    float* out = (float*)d_out;

    const int* src = eidx;
    const int* dst = eidx + NE;

    // workspace layout (4-byte units). Zeroed region is contiguous & first.
    char* base = (char*)d_ws;
    int*   hist     = (int*)base;                       // NN
    float* cnt      = (float*)(hist + NN);              // NN
    float* agg      = cnt + NN;                         // NN*32
    float* pooled   = agg + (size_t)NN * 32;            // NG*HID
    float* gcnt     = pooled + NG * HID;                // NG
    size_t zero_bytes = ((size_t)NN + NN + (size_t)NN * 32 + NG * HID + NG) * 4;
    int*   rowStart = (int*)(gcnt + NG);                // NN+1
    int*   cursor   = rowStart + NN + 1;                // NN
    float* ea_s     = (float*)(cursor + NN);            // NE*9
    int*   src_s    = (int*)(ea_s + (size_t)NE * EAD);  // NE
    int*   dst_s    = src_s + NE;                       // NE
    float* h1       = (float*)(dst_s + NE);             // NN*32
    float* h2       = h1 + (size_t)NN * 32;             // NN*32

    hipMemsetAsync(hist, 0, zero_bytes, stream);

    // ---- sort edges by src (counting sort), reused by both convs ----
    edge_stats_kernel<<<(NE + 255) / 256, 256, 0, stream>>>(src, dst, hist, cnt);
    scan_kernel<<<1, 1024, 0, stream>>>(hist, rowStart, cursor);
    scatter_kernel<<<(NE + 255) / 256, 256, 0, stream>>>(ea, src, dst, cursor,
                                                         ea_s, src_s, dst_s);

    // ---- conv1 ----
    conv_node_kernel<FEAT><<<NN / 8, 256, 0, stream>>>(
        x, nn1_w1, nn1_b1, nn1_w2, nn1_b2, rowStart, ea_s, src_s, dst_s, agg);
    node_update_kernel<FEAT><<<(NN * 32) / 256, 256, 0, stream>>>(
        agg, cnt, x, root1, bias1, h1, nullptr, nullptr, nullptr);

    // ---- conv2 ----
    hipMemsetAsync(agg, 0, (size_t)NN * 32 * sizeof(float), stream);
    conv_node_kernel<EMB><<<NN / 8, 256, 0, stream>>>(
        h1, nn2_w1, nn2_b1, nn2_w2, nn2_b2, rowStart, ea_s, src_s, dst_s, agg);
    node_update_kernel<EMB><<<(NN * 32) / 256, 256, 0, stream>>>(
        agg, cnt, h1, root2, bias2, h2, pooled, batch, gcnt);

    // ---- head ----
    final_kernel<<<1, 64, 0, stream>>>(pooled, gcnt, lin_w, lin_b, out);
}

// Round 4
// 390.225 us; speedup vs baseline: 1.2878x; 1.0687x over previous
//
#include <hip/hip_runtime.h>
#include <hip/hip_bf16.h>

#define NN 10000
#define NE 250000
#define FEAT 16
#define EMB 32
#define HID 32
#define NV 12
#define EAD 9
#define NG 64
#define EPB 128  // edges per block in edge_msg

// ---------------------------------------------------------------------------
// src/dst out-degree histograms
// ---------------------------------------------------------------------------
__global__ void edge_stats_kernel(const int* __restrict__ src,
                                  const int* __restrict__ dst,
                                  int* __restrict__ histS,
                                  int* __restrict__ histD) {
    int e = blockIdx.x * blockDim.x + threadIdx.x;
    if (e >= NE) return;
    atomicAdd(&histS[src[e]], 1);
    atomicAdd(&histD[dst[e]], 1);
}

// ---------------------------------------------------------------------------
// Single-block exclusive scan of hist[NN] -> rowStart[NN+1], cursor[NN]
// ---------------------------------------------------------------------------
__global__ __launch_bounds__(1024) void scan_kernel(const int* __restrict__ hist,
                                                    int* __restrict__ rowStart,
                                                    int* __restrict__ cursor) {
    __shared__ int part[1024];
    int t = threadIdx.x;
    int base = t * 10;
    int local[10];
    int s = 0;
#pragma unroll
    for (int i = 0; i < 10; ++i) {
        int v = (base + i < NN) ? hist[base + i] : 0;
        local[i] = s;
        s += v;
    }
    part[t] = s;
    __syncthreads();
    for (int off = 1; off < 1024; off <<= 1) {
        int v = (t >= off) ? part[t - off] : 0;
        __syncthreads();
        part[t] += v;
        __syncthreads();
    }
    int pre = (t == 0) ? 0 : part[t - 1];
#pragma unroll
    for (int i = 0; i < 10; ++i) {
        if (base + i < NN) {
            int rs = pre + local[i];
            rowStart[base + i] = rs;
            cursor[base + i] = rs;
        }
    }
    if (t == 1023) rowStart[NN] = part[1023];
}

// ---------------------------------------------------------------------------
// Permute edges into src-sorted order; record dst-sorted position per edge.
// ---------------------------------------------------------------------------
__global__ void scatter_kernel(const float* __restrict__ ea,
                               const int* __restrict__ src,
                               const int* __restrict__ dst,
                               int* __restrict__ cursorS,
                               int* __restrict__ cursorD,
                               float* __restrict__ ea_s,
                               int* __restrict__ src_s,
                               int* __restrict__ perm_d) {
    int e = blockIdx.x * blockDim.x + threadIdx.x;
    if (e >= NE) return;
    int sv = src[e], dv = dst[e];
    int pos  = atomicAdd(&cursorS[sv], 1);
    int posd = atomicAdd(&cursorD[dv], 1);
    src_s[pos] = sv;
    perm_d[pos] = posd;
#pragma unroll
    for (int j = 0; j < EAD; ++j) ea_s[(size_t)pos * EAD + j] = ea[(size_t)e * EAD + j];
}

// ---------------------------------------------------------------------------
// Q[n,k,o] = sum_i h[n,i]*w2[k,i*32+o]  (k<32);  Q[n,32,o] = sum_i h[n,i]*b2[i*32+o]
// ---------------------------------------------------------------------------
template <int DIN>
__global__ void computeQ_kernel(const float* __restrict__ h,
                                const float* __restrict__ w2,
                                const float* __restrict__ b2,
                                float* __restrict__ Q) {
    int idx = blockIdx.x * blockDim.x + threadIdx.x;
    if (idx >= NN * 33 * 32) return;
    int o = idx & 31;
    int k = (idx >> 5) % 33;
    int n = idx / (33 * 32);
    const float* hn = h + (size_t)n * DIN;
    float s = 0.f;
    if (k < 32) {
        const float* w = w2 + (size_t)k * (DIN * 32);
#pragma unroll
        for (int i = 0; i < DIN; ++i) s += hn[i] * w[i * 32 + o];
    } else {
#pragma unroll
        for (int i = 0; i < DIN; ++i) s += hn[i] * b2[i * 32 + o];
    }
    Q[idx] = s;
}

// ---------------------------------------------------------------------------
// Edge messages: 32 lanes per edge, no LDS, no barriers, no atomics.
// hidden[o] = relu(ea@w1+b1)[o] per lane; share via __shfl within the 32-group;
// msg[o] = Q[src,32,o] + sum_k hidden[k]*Q[src,k,o]; store at dst-sorted slot.
// ---------------------------------------------------------------------------
__global__ __launch_bounds__(256) void edge_msg_kernel(
    const float* __restrict__ ea_s,
    const int* __restrict__ src_s,
    const int* __restrict__ perm_d,
    const float* __restrict__ w1,   // [9,32]
    const float* __restrict__ b1,   // [32]
    const float* __restrict__ Q,    // [N,33,32]
    float* __restrict__ msg)        // [E,32] in dst-sorted order
{
    int t = threadIdx.x;
    int o = t & 31;
    float w1r[EAD];
#pragma unroll
    for (int j = 0; j < EAD; ++j) w1r[j] = w1[j * 32 + o];
    float b1r = b1[o];

    int base = blockIdx.x * EPB;
    int eend = min(base + EPB, NE);
    for (int e = base + (t >> 5); e < eend; e += 8) {
        const float* eav = ea_s + (size_t)e * EAD;
        float hs = b1r;
#pragma unroll
        for (int j = 0; j < EAD; ++j) hs += eav[j] * w1r[j];
        float hd = fmaxf(hs, 0.f);

        const float* q = Q + (size_t)src_s[e] * (33 * 32);
        float m = q[32 * 32 + o];
#pragma unroll
        for (int k = 0; k < 32; ++k) m += __shfl(hd, k, 32) * q[k * 32 + o];

        msg[(size_t)perm_d[e] * 32 + o] = m;
    }
}

// ---------------------------------------------------------------------------
// Per-dst segmented sum over contiguous msg rows + mean + root matmul + bias
// + ReLU; optional fused graph pooling.
// ---------------------------------------------------------------------------
template <int DIN>
__global__ __launch_bounds__(256) void aggregate_kernel(
    const float* __restrict__ msg,
    const int* __restrict__ dRow,    // [N+1]
    const float* __restrict__ hin,   // [N,DIN]
    const float* __restrict__ root,  // [DIN,32]
    const float* __restrict__ bias,  // [32]
    float* __restrict__ hout,        // [N,32]
    float* __restrict__ pooled,      // [G,32] or null
    const int* __restrict__ batch,
    float* __restrict__ gcnt)        // [G] or null
{
    int t = threadIdx.x;
    int o = t & 31;
    int n = blockIdx.x * 8 + (t >> 5);
    int beg = dRow[n], end = dRow[n + 1];
    float s = 0.f;
    for (int r = beg; r < end; ++r) s += msg[(size_t)r * 32 + o];
    s /= fmaxf((float)(end - beg), 1.0f);
    s += bias[o];
    const float* h = hin + (size_t)n * DIN;
#pragma unroll
    for (int i = 0; i < DIN; ++i) s += h[i] * root[i * 32 + o];
    s = fmaxf(s, 0.f);
    hout[(size_t)n * 32 + o] = s;
    if (pooled) {
        int g = batch[n];
        atomicAdd(&pooled[g * 32 + o], s);
        if (o == 0) atomicAdd(&gcnt[g], 1.0f);
    }
}

// ---------------------------------------------------------------------------
// Final: pooled mean -> linear(32,12) -> log_softmax.
// ---------------------------------------------------------------------------
__global__ void final_kernel(const float* __restrict__ pooled,
                             const float* __restrict__ gcnt,
                             const float* __restrict__ lin_w,
                             const float* __restrict__ lin_b,
                             float* __restrict__ out) {
    int g = threadIdx.x;
    if (g >= NG) return;
    float inv = 1.0f / fmaxf(gcnt[g], 1.0f);
    float p[HID];
#pragma unroll
    for (int h = 0; h < HID; ++h) p[h] = pooled[g * HID + h] * inv;
    float logits[NV];
    float mx = -1e30f;
#pragma unroll
    for (int v = 0; v < NV; ++v) {
        float s = lin_b[v];
#pragma unroll
        for (int h = 0; h < HID; ++h) s += p[h] * lin_w[h * NV + v];
        logits[v] = s;
        mx = fmaxf(mx, s);
    }
    float se = 0.f;
#pragma unroll
    for (int v = 0; v < NV; ++v) se += expf(logits[v] - mx);
    float lse = mx + logf(se);
#pragma unroll
    for (int v = 0; v < NV; ++v) out[g * NV + v] = logits[v] - lse;
}

// ---------------------------------------------------------------------------
extern "C" void kernel_launch(void* const* d_in, const int* in_sizes, int n_in,
                              void* d_out, int out_size, void* d_ws, size_t ws_size,
                              hipStream_t stream) {
    const float* x        = (const float*)d_in[0];
    const float* ea       = (const float*)d_in[1];
    const int*   eidx     = (const int*)d_in[2];
    const int*   batch    = (const int*)d_in[3];
    const float* nn1_w1   = (const float*)d_in[4];
    const float* nn1_b1   = (const float*)d_in[5];
    const float* nn1_w2   = (const float*)d_in[6];
    const float* nn1_b2   = (const float*)d_in[7];
    const float* root1    = (const float*)d_in[8];
    const float* bias1    = (const float*)d_in[9];
    const float* nn2_w1   = (const float*)d_in[10];
    const float* nn2_b1   = (const float*)d_in[11];
    const float* nn2_w2   = (const float*)d_in[12];
    const float* nn2_b2   = (const float*)d_in[13];
    const float* root2    = (const float*)d_in[14];
    const float* bias2    = (const float*)d_in[15];
    const float* lin_w    = (const float*)d_in[16];
    const float* lin_b    = (const float*)d_in[17];
    float* out = (float*)d_out;

    const int* src = eidx;
    const int* dst = eidx + NE;

    // workspace layout (zeroed region first & contiguous)
    char* base = (char*)d_ws;
    int*   histS   = (int*)base;                        // NN
    int*   histD   = histS + NN;                        // NN
    float* pooled  = (float*)(histD + NN);              // NG*32
    float* gcnt    = pooled + NG * 32;                  // NG
    size_t zero_bytes = ((size_t)NN * 2 + NG * 32 + NG) * 4;
    int*   rowS    = (int*)(gcnt + NG);                 // NN+1
    int*   rowD    = rowS + NN + 1;                     // NN+1
    int*   curS    = rowD + NN + 1;                     // NN
    int*   curD    = curS + NN;                         // NN
    float* ea_s    = (float*)(curD + NN);               // NE*9
    int*   src_s   = (int*)(ea_s + (size_t)NE * EAD);   // NE
    int*   perm_d  = src_s + NE;                        // NE
    float* Q       = (float*)(perm_d + NE);             // NN*33*32
    float* msg     = Q + (size_t)NN * 33 * 32;          // NE*32
    float* h1      = msg + (size_t)NE * 32;             // NN*32
    float* h2      = h1 + (size_t)NN * 32;              // NN*32

    hipMemsetAsync(histS, 0, zero_bytes, stream);

    // ---- edge sort pre-pass (shared by both convs) ----
    edge_stats_kernel<<<(NE + 255) / 256, 256, 0, stream>>>(src, dst, histS, histD);
    scan_kernel<<<1, 1024, 0, stream>>>(histS, rowS, curS);
    scan_kernel<<<1, 1024, 0, stream>>>(histD, rowD, curD);
    scatter_kernel<<<(NE + 255) / 256, 256, 0, stream>>>(ea, src, dst, curS, curD,
                                                         ea_s, src_s, perm_d);

    const int edge_grid = (NE + EPB - 1) / EPB;

    // ---- conv1 ----
    computeQ_kernel<FEAT><<<(NN * 33 * 32) / 256, 256, 0, stream>>>(x, nn1_w2, nn1_b2, Q);
    edge_msg_kernel<<<edge_grid, 256, 0, stream>>>(ea_s, src_s, perm_d, nn1_w1, nn1_b1, Q, msg);
    aggregate_kernel<FEAT><<<NN / 8, 256, 0, stream>>>(
        msg, rowD, x, root1, bias1, h1, nullptr, nullptr, nullptr);

    // ---- conv2 ----
    computeQ_kernel<EMB><<<(NN * 33 * 32) / 256, 256, 0, stream>>>(h1, nn2_w2, nn2_b2, Q);
    edge_msg_kernel<<<edge_grid, 256, 0, stream>>>(ea_s, src_s, perm_d, nn2_w1, nn2_b1, Q, msg);
    aggregate_kernel<EMB><<<NN / 8, 256, 0, stream>>>(
        msg, rowD, h1, root2, bias2, h2, pooled, batch, gcnt);

    // ---- head ----
    final_kernel<<<1, 64, 0, stream>>>(pooled, gcnt, lin_w, lin_b, out);
}

// Round 5
// 299.532 us; speedup vs baseline: 1.6778x; 1.3028x over previous
//
#include <hip/hip_runtime.h>
#include <hip/hip_bf16.h>
#include <stdint.h>

#define NN 10000
#define NE 250000
#define FEAT 16
#define EMB 32
#define HID 32
#define NV 12
#define EAD 9
#define NG 64
#define EPB 128   // edges per block in edge_msg
#define NCH 25    // nodes per block in computeQ_pack

__device__ __forceinline__ uint32_t bf16rne(float f) {
    uint32_t u = __float_as_uint(f);
    return (u + 0x7fffu + ((u >> 16) & 1u)) >> 16;
}
__device__ __forceinline__ float blo(uint32_t p) { return __uint_as_float(p << 16); }
__device__ __forceinline__ float bhi(uint32_t p) { return __uint_as_float(p & 0xffff0000u); }

// ---------------------------------------------------------------------------
// src/dst degree histograms
// ---------------------------------------------------------------------------
__global__ void edge_stats_kernel(const int* __restrict__ src,
                                  const int* __restrict__ dst,
                                  int* __restrict__ histS,
                                  int* __restrict__ histD) {
    int e = blockIdx.x * blockDim.x + threadIdx.x;
    if (e >= NE) return;
    atomicAdd(&histS[src[e]], 1);
    atomicAdd(&histD[dst[e]], 1);
}

// ---------------------------------------------------------------------------
// Exclusive scan of hist[NN] -> rowStart[NN+1], cursor[NN]. grid=2: block 0
// scans histS, block 1 scans histD.
// ---------------------------------------------------------------------------
__global__ __launch_bounds__(1024) void scan_kernel(const int* __restrict__ histS,
                                                    const int* __restrict__ histD,
                                                    int* __restrict__ rowS,
                                                    int* __restrict__ rowD,
                                                    int* __restrict__ curS,
                                                    int* __restrict__ curD) {
    const int* hist = blockIdx.x ? histD : histS;
    int* rowStart   = blockIdx.x ? rowD : rowS;
    int* cursor     = blockIdx.x ? curD : curS;
    __shared__ int part[1024];
    int t = threadIdx.x;
    int base = t * 10;
    int local[10];
    int s = 0;
#pragma unroll
    for (int i = 0; i < 10; ++i) {
        int v = (base + i < NN) ? hist[base + i] : 0;
        local[i] = s;
        s += v;
    }
    part[t] = s;
    __syncthreads();
    for (int off = 1; off < 1024; off <<= 1) {
        int v = (t >= off) ? part[t - off] : 0;
        __syncthreads();
        part[t] += v;
        __syncthreads();
    }
    int pre = (t == 0) ? 0 : part[t - 1];
#pragma unroll
    for (int i = 0; i < 10; ++i) {
        if (base + i < NN) {
            int rs = pre + local[i];
            rowStart[base + i] = rs;
            cursor[base + i] = rs;
        }
    }
    if (t == 1023) rowStart[NN] = part[1023];
}

// ---------------------------------------------------------------------------
// Permute edges to src-sorted order (ea padded to 12 floats for float4 loads);
// record each edge's dst-sorted slot.
// ---------------------------------------------------------------------------
__global__ void scatter_kernel(const float* __restrict__ ea,
                               const int* __restrict__ src,
                               const int* __restrict__ dst,
                               int* __restrict__ cursorS,
                               int* __restrict__ cursorD,
                               float* __restrict__ ea_p,   // [E,12]
                               int* __restrict__ src_s,
                               int* __restrict__ perm_d) {
    int e = blockIdx.x * blockDim.x + threadIdx.x;
    if (e >= NE) return;
    int sv = src[e], dv = dst[e];
    int pos  = atomicAdd(&cursorS[sv], 1);
    int posd = atomicAdd(&cursorD[dv], 1);
    src_s[pos] = sv;
    perm_d[pos] = posd;
#pragma unroll
    for (int j = 0; j < 12; ++j)
        ea_p[(size_t)pos * 12 + j] = (j < EAD) ? ea[(size_t)e * EAD + j] : 0.f;
}

// ---------------------------------------------------------------------------
// Qp[n][kk][o] (kk=0..15) = packed bf16 pair (k=2kk lo, k=2kk+1 hi) of
// Q[n,k,o] = sum_i h[n,i]*w2[k, i*32+o].
// Thread owns (kk,o) with both w2 columns in registers; loops NCH nodes whose
// h rows are wave-uniform -> scalar loads.
// ---------------------------------------------------------------------------
template <int DIN>
__global__ __launch_bounds__(256) void computeQ_pack_kernel(
    const float* __restrict__ h,    // [N,DIN]
    const float* __restrict__ w2,   // [32, DIN*32]
    uint32_t* __restrict__ Qp)      // [N,16,32]
{
    int t = threadIdx.x;
    int o = t & 31;
    int kk = (blockIdx.y * 256 + t) >> 5;  // 0..15
    float w0[DIN], w1r[DIN];
    const float* wa = w2 + (size_t)(2 * kk) * (DIN * 32) + o;
    const float* wb = w2 + (size_t)(2 * kk + 1) * (DIN * 32) + o;
#pragma unroll
    for (int i = 0; i < DIN; ++i) { w0[i] = wa[i * 32]; w1r[i] = wb[i * 32]; }

    int n0 = blockIdx.x * NCH;
    for (int j = 0; j < NCH; ++j) {
        int n = n0 + j;
        const float* hn = h + (size_t)n * DIN;   // wave-uniform -> s_load
        float s0 = 0.f, s1 = 0.f;
#pragma unroll
        for (int i = 0; i < DIN; ++i) {
            float hv = hn[i];
            s0 += hv * w0[i];
            s1 += hv * w1r[i];
        }
        Qp[((size_t)n * 16 + kk) * 32 + o] = (bf16rne(s1) << 16) | bf16rne(s0);
    }
}

// ---------------------------------------------------------------------------
// Qb[n,o] = sum_i h[n,i]*b2[i*32+o]  (fp32 bias row)
// ---------------------------------------------------------------------------
template <int DIN>
__global__ void computeQbias_kernel(const float* __restrict__ h,
                                    const float* __restrict__ b2,
                                    float* __restrict__ Qb) {
    int idx = blockIdx.x * blockDim.x + threadIdx.x;
    if (idx >= NN * 32) return;
    int o = idx & 31;
    int n = idx >> 5;
    const float* hn = h + (size_t)n * DIN;
    float s = 0.f;
#pragma unroll
    for (int i = 0; i < DIN; ++i) s += hn[i] * b2[i * 32 + o];
    Qb[idx] = s;
}

// ---------------------------------------------------------------------------
// Edge messages. 32 lanes/edge: edge-MLP (3x float4), hidden staged via one
// ds_write + broadcast ds_read_b128; Q gathered as bf16 pairs; store at
// dst-sorted slot. No barriers (intra-wave LDS only), no atomics.
// ---------------------------------------------------------------------------
__global__ __launch_bounds__(256) void edge_msg_kernel(
    const float* __restrict__ ea_p,   // [E,12]
    const int* __restrict__ src_s,
    const int* __restrict__ perm_d,
    const float* __restrict__ w1,     // [9,32]
    const float* __restrict__ b1,     // [32]
    const uint32_t* __restrict__ Qp,  // [N,16,32]
    const float* __restrict__ Qb,     // [N,32]
    float* __restrict__ msg)          // [E,32] dst-sorted
{
    __shared__ float s_hid[8][32];
    int t = threadIdx.x;
    int o = t & 31;
    int slot = t >> 5;

    float w1r[12];
#pragma unroll
    for (int j = 0; j < 12; ++j) w1r[j] = (j < EAD) ? w1[j * 32 + o] : 0.f;
    float b1r = b1[o];

    int base = blockIdx.x * EPB;
    int eend = min(base + EPB, NE);
    for (int e = base + slot; e < eend; e += 8) {
        const float4* eav = (const float4*)(ea_p + (size_t)e * 12);
        float4 a0 = eav[0], a1 = eav[1], a2 = eav[2];
        float hs = b1r;
        hs += a0.x * w1r[0] + a0.y * w1r[1] + a0.z * w1r[2] + a0.w * w1r[3];
        hs += a1.x * w1r[4] + a1.y * w1r[5] + a1.z * w1r[6] + a1.w * w1r[7];
        hs += a2.x * w1r[8];
        float hd = fmaxf(hs, 0.f);

        s_hid[slot][o] = hd;
        __builtin_amdgcn_wave_barrier();   // keep compiler from hoisting reads

        int sv = src_s[e];
        const uint32_t* q = Qp + (size_t)sv * 512 + o;
        float m = Qb[(size_t)sv * 32 + o];
        const float4* hq = (const float4*)(&s_hid[slot][0]);
#pragma unroll
        for (int c = 0; c < 8; ++c) {
            float4 hv = hq[c];                 // broadcast ds_read_b128
            uint32_t qa = q[(2 * c) * 32];     // pair k=4c,4c+1
            uint32_t qb2 = q[(2 * c + 1) * 32];// pair k=4c+2,4c+3
            m += hv.x * blo(qa) + hv.y * bhi(qa)
               + hv.z * blo(qb2) + hv.w * bhi(qb2);
        }
        msg[(size_t)perm_d[e] * 32 + o] = m;
        __builtin_amdgcn_wave_barrier();   // don't let next ds_write pass reads
    }
}

// ---------------------------------------------------------------------------
// Segmented mean over contiguous msg rows + root matmul + bias + ReLU;
// optional fused graph pooling.
// ---------------------------------------------------------------------------
template <int DIN>
__global__ __launch_bounds__(256) void aggregate_kernel(
    const float* __restrict__ msg,
    const int* __restrict__ dRow,
    const float* __restrict__ hin,
    const float* __restrict__ root,
    const float* __restrict__ bias,
    float* __restrict__ hout,
    float* __restrict__ pooled,
    const int* __restrict__ batch,
    float* __restrict__ gcnt)
{
    int t = threadIdx.x;
    int o = t & 31;
    int n = blockIdx.x * 8 + (t >> 5);
    int beg = dRow[n], end = dRow[n + 1];
    float s = 0.f;
    for (int r = beg; r < end; ++r) s += msg[(size_t)r * 32 + o];
    s /= fmaxf((float)(end - beg), 1.0f);
    s += bias[o];
    const float* h = hin + (size_t)n * DIN;
#pragma unroll
    for (int i = 0; i < DIN; ++i) s += h[i] * root[i * 32 + o];
    s = fmaxf(s, 0.f);
    hout[(size_t)n * 32 + o] = s;
    if (pooled) {
        int g = batch[n];
        atomicAdd(&pooled[g * 32 + o], s);
        if (o == 0) atomicAdd(&gcnt[g], 1.0f);
    }
}

// ---------------------------------------------------------------------------
// pooled mean -> linear(32,12) -> log_softmax
// ---------------------------------------------------------------------------
__global__ void final_kernel(const float* __restrict__ pooled,
                             const float* __restrict__ gcnt,
                             const float* __restrict__ lin_w,
                             const float* __restrict__ lin_b,
                             float* __restrict__ out) {
    int g = threadIdx.x;
    if (g >= NG) return;
    float inv = 1.0f / fmaxf(gcnt[g], 1.0f);
    float p[HID];
#pragma unroll
    for (int h = 0; h < HID; ++h) p[h] = pooled[g * HID + h] * inv;
    float logits[NV];
    float mx = -1e30f;
#pragma unroll
    for (int v = 0; v < NV; ++v) {
        float s = lin_b[v];
#pragma unroll
        for (int h = 0; h < HID; ++h) s += p[h] * lin_w[h * NV + v];
        logits[v] = s;
        mx = fmaxf(mx, s);
    }
    float se = 0.f;
#pragma unroll
    for (int v = 0; v < NV; ++v) se += expf(logits[v] - mx);
    float lse = mx + logf(se);
#pragma unroll
    for (int v = 0; v < NV; ++v) out[g * NV + v] = logits[v] - lse;
}

// ---------------------------------------------------------------------------
extern "C" void kernel_launch(void* const* d_in, const int* in_sizes, int n_in,
                              void* d_out, int out_size, void* d_ws, size_t ws_size,
                              hipStream_t stream) {
    const float* x        = (const float*)d_in[0];
    const float* ea       = (const float*)d_in[1];
    const int*   eidx     = (const int*)d_in[2];
    const int*   batch    = (const int*)d_in[3];
    const float* nn1_w1   = (const float*)d_in[4];
    const float* nn1_b1   = (const float*)d_in[5];
    const float* nn1_w2   = (const float*)d_in[6];
    const float* nn1_b2   = (const float*)d_in[7];
    const float* root1    = (const float*)d_in[8];
    const float* bias1    = (const float*)d_in[9];
    const float* nn2_w1   = (const float*)d_in[10];
    const float* nn2_b1   = (const float*)d_in[11];
    const float* nn2_w2   = (const float*)d_in[12];
    const float* nn2_b2   = (const float*)d_in[13];
    const float* root2    = (const float*)d_in[14];
    const float* bias2    = (const float*)d_in[15];
    const float* lin_w    = (const float*)d_in[16];
    const float* lin_b    = (const float*)d_in[17];
    float* out = (float*)d_out;

    const int* src = eidx;
    const int* dst = eidx + NE;

    // workspace layout: 16B-aligned big arrays first, then ints, then the
    // contiguous zeroed region.
    char* base = (char*)d_ws;
    uint32_t* Qp   = (uint32_t*)base;                       // NN*512
    float* msg     = (float*)(Qp + (size_t)NN * 512);       // NE*32
    float* ea_p    = msg + (size_t)NE * 32;                 // NE*12
    float* Qb      = ea_p + (size_t)NE * 12;                // NN*32
    float* h1      = Qb + (size_t)NN * 32;                  // NN*32
    float* h2      = h1 + (size_t)NN * 32;                  // NN*32
    int*   src_s   = (int*)(h2 + (size_t)NN * 32);          // NE
    int*   perm_d  = src_s + NE;                            // NE
    int*   rowS    = perm_d + NE;                           // NN+1
    int*   rowD    = rowS + NN + 1;                         // NN+1
    int*   curS    = rowD + NN + 1;                         // NN
    int*   curD    = curS + NN;                             // NN
    int*   histS   = curD + NN;                             // NN   (zeroed from here)
    int*   histD   = histS + NN;                            // NN
    float* pooled  = (float*)(histD + NN);                  // NG*32
    float* gcnt    = pooled + NG * 32;                      // NG
    size_t zero_bytes = ((size_t)NN * 2 + NG * 32 + NG) * 4;

    hipMemsetAsync(histS, 0, zero_bytes, stream);

    // ---- edge sort pre-pass (shared by both convs) ----
    edge_stats_kernel<<<(NE + 255) / 256, 256, 0, stream>>>(src, dst, histS, histD);
    scan_kernel<<<2, 1024, 0, stream>>>(histS, histD, rowS, rowD, curS, curD);
    scatter_kernel<<<(NE + 255) / 256, 256, 0, stream>>>(ea, src, dst, curS, curD,
                                                         ea_p, src_s, perm_d);

    const int edge_grid = (NE + EPB - 1) / EPB;
    dim3 qgrid(NN / NCH, 2);

    // ---- conv1 ----
    computeQ_pack_kernel<FEAT><<<qgrid, 256, 0, stream>>>(x, nn1_w2, Qp);
    computeQbias_kernel<FEAT><<<(NN * 32) / 256, 256, 0, stream>>>(x, nn1_b2, Qb);
    edge_msg_kernel<<<edge_grid, 256, 0, stream>>>(ea_p, src_s, perm_d,
                                                   nn1_w1, nn1_b1, Qp, Qb, msg);
    aggregate_kernel<FEAT><<<NN / 8, 256, 0, stream>>>(
        msg, rowD, x, root1, bias1, h1, nullptr, nullptr, nullptr);

    // ---- conv2 ----
    computeQ_pack_kernel<EMB><<<qgrid, 256, 0, stream>>>(h1, nn2_w2, Qp);
    computeQbias_kernel<EMB><<<(NN * 32) / 256, 256, 0, stream>>>(h1, nn2_b2, Qb);
    edge_msg_kernel<<<edge_grid, 256, 0, stream>>>(ea_p, src_s, perm_d,
                                                   nn2_w1, nn2_b1, Qp, Qb, msg);
    aggregate_kernel<EMB><<<NN / 8, 256, 0, stream>>>(
        msg, rowD, h1, root2, bias2, h2, pooled, batch, gcnt);

    // ---- head ----
    final_kernel<<<1, 64, 0, stream>>>(pooled, gcnt, lin_w, lin_b, out);
}